// Round 3
// baseline (897.149 us; speedup 1.0000x reference)
//
#include <hip/hip_runtime.h>
#include <hip/hip_bf16.h>
#include <math.h>

#define Bsz 16384
#define HIDc 1024

typedef __attribute__((ext_vector_type(8))) short short8_t;
typedef __attribute__((ext_vector_type(4))) float f32x4;
typedef __attribute__((ext_vector_type(4))) short s16x4;

typedef __attribute__((address_space(1))) const unsigned char* gp1_t;
typedef __attribute__((address_space(3))) unsigned char* lp3_t;

__device__ __forceinline__ float sigf(float x) { return 1.0f / (1.0f + __expf(-x)); }
__device__ __forceinline__ float tanh_fast(float x) {
  x = fminf(fmaxf(x, -10.f), 10.f);
  float t = __expf(2.f * x);
  return (t - 1.f) / (t + 1.f);
}

// Bijective XCD-chunked swizzle (T1, m204 form): XCD x owns a contiguous chunk
// of flat block ids, so blocks sharing an A-panel co-run on one XCD's L2.
// r2 evidence: final_k FETCH 573 MB -> 280 MB. Keep.
__device__ __forceinline__ int xcd_map(int bid, int nwg) {
  const int q = nwg >> 3, r = nwg & 7;
  const int xcd = bid & 7, idx = bid >> 3;
  return (xcd < r ? xcd * (q + 1) : r * (q + 1) + (xcd - r) * q) + idx;
}

// Stage a 128x64 bf16 tile (16 KB) into LDS with global_load_lds width=16.
// LDS dest linear; k-slot XOR swizzle applied on the GLOBAL source address
// (both-sides-or-neither, rule #21): phys slot p of row r holds logical p^(r&7).
__device__ __forceinline__ void stage64(const __hip_bfloat16* __restrict__ g, long ld,
                                        __hip_bfloat16* l, int wave, int lane) {
  const int rsub = lane >> 3;                    // row within 8-row chunk
  const int kx = ((lane & 7) ^ rsub) << 3;       // swizzled source col (elems)
#pragma unroll
  for (int i = 0; i < 4; ++i) {
    const int chunk = i * 4 + wave;              // 0..15, 8 rows each
    const int row = chunk * 8 + rsub;
    const __hip_bfloat16* gp = g + (long)row * ld + kx;
    __hip_bfloat16* lp = l + chunk * 512 + lane * 8;   // chunk*1024B + lane*16B
    __builtin_amdgcn_global_load_lds((gp1_t)gp, (lp3_t)lp, 16, 0, 0);
  }
}

// Serial m97-style K-loop (32 KB LDS). r2 post-mortem: 64 KB dbuf halved
// occupancy (42.6% -> 22.3%) and regressed; latency-bound kernels here live
// off TLP, so keep the 2-barrier serial schedule.
__device__ __forceinline__ void gemm_acc(const __hip_bfloat16* __restrict__ A, long lda,
                                         const __hip_bfloat16* __restrict__ Wt, long ldw,
                                         int K,
                                         __hip_bfloat16* lA, __hip_bfloat16* lB,
                                         f32x4 acc[4][4]) {
  const int tid = threadIdx.x;
  const int wave = tid >> 6, lane = tid & 63;
  const int wr = wave >> 1, wc = wave & 1;
  const int lm = lane & 15, hi = lane >> 4, l7 = lane & 7;
  for (int k0 = 0; k0 < K; k0 += 64) {
    __syncthreads();                       // previous compute done before overwrite
    stage64(A + k0, lda, lA, wave, lane);
    stage64(Wt + k0, ldw, lB, wave, lane);
    __syncthreads();                       // compiler drains vmcnt before barrier
#pragma unroll
    for (int ks = 0; ks < 2; ++ks) {
      short8_t a8[4], b8[4];
      const int sl = ks * 4 + hi;          // logical 16B slot 0..7
#pragma unroll
      for (int m = 0; m < 4; ++m) {
        const int r = wr * 64 + m * 16 + lm;
        a8[m] = *reinterpret_cast<const short8_t*>(lA + r * 64 + ((sl ^ l7) << 3));
      }
#pragma unroll
      for (int n = 0; n < 4; ++n) {
        const int r = wc * 64 + n * 16 + lm;
        b8[n] = *reinterpret_cast<const short8_t*>(lB + r * 64 + ((sl ^ l7) << 3));
      }
#pragma unroll
      for (int m = 0; m < 4; ++m)
#pragma unroll
        for (int n = 0; n < 4; ++n)
          acc[m][n] = __builtin_amdgcn_mfma_f32_16x16x32_bf16(a8[m], b8[n], acc[m][n], 0, 0, 0);
    }
  }
}

// EPI 0: G1 ru — col<1024: rs = sigmoid(v+br)*state_bf16 -> out0 (bf16, ld 1024)
//                col>=1024: u = sigmoid(v+bu)            -> out1 (bf16, ld 1024)
// EPI 1: G2     — col<1024: sem = relu(v+b1) -> out0 (bf16, ld 2048)
//                col>=1024: cx = v+bc        -> out1 (bf16, ld 1024)
// EPI 2: G3     — nei = relu(v+b2) -> out0 + 1024 (bf16, ld 2048)
template <int EPI>
__global__ void gemm_k(const __hip_bfloat16* __restrict__ A, long lda,
                       const __hip_bfloat16* __restrict__ Wt, long ldw, int K, int nbx,
                       const float* __restrict__ bias0, const float* __restrict__ bias1,
                       const __hip_bfloat16* __restrict__ stbf,   // A1 (state at col 1024+)
                       __hip_bfloat16* __restrict__ out0, __hip_bfloat16* __restrict__ out1) {
  __shared__ __hip_bfloat16 lA[128 * 64], lB[128 * 64];
  f32x4 acc[4][4];
#pragma unroll
  for (int m = 0; m < 4; ++m)
#pragma unroll
    for (int n = 0; n < 4; ++n) acc[m][n] = (f32x4){0.f, 0.f, 0.f, 0.f};

  const int wg = xcd_map(blockIdx.x, gridDim.x);
  const long mBase = (long)(wg / nbx) * 128;
  const long nBase = (long)(wg % nbx) * 128;
  gemm_acc(A + mBase * lda, lda, Wt + nBase * ldw, ldw, K, lA, lB, acc);

  const int tid = threadIdx.x, wave = tid >> 6, lane = tid & 63;
  const int wr = wave >> 1, wc = wave & 1, lm = lane & 15, hi = lane >> 4;
  const int row0 = (int)mBase + wr * 64 + hi * 4;
  const int col0 = (int)nBase + wc * 64 + lm;
#pragma unroll
  for (int m = 0; m < 4; ++m)
#pragma unroll
    for (int n = 0; n < 4; ++n)
#pragma unroll
      for (int j = 0; j < 4; ++j) {
        const long row = row0 + m * 16 + j;
        const int col = col0 + n * 16;
        const float v = acc[m][n][j];
        if (EPI == 0) {
          if (col < HIDc) {
            float rr = sigf(v + bias0[col]);
            float st = __bfloat162float(stbf[row * 2048 + 1024 + col]);
            out0[row * HIDc + col] = __float2bfloat16(rr * st);
          } else {
            int c = col - HIDc;
            out1[row * HIDc + c] = __float2bfloat16(sigf(v + bias1[c]));
          }
        } else if (EPI == 1) {
          if (col < HIDc) {
            out0[row * 2048 + col] = __float2bfloat16(fmaxf(v + bias0[col], 0.f));
          } else {
            int c = col - HIDc;
            out1[row * HIDc + c] = __float2bfloat16(v + bias1[c]);
          }
        } else {
          out0[row * 2048 + HIDc + col] = __float2bfloat16(fmaxf(v + bias0[col], 0.f));
        }
      }
}

// G4: accC = RS @ Wcb^T (K=1024); accG = [sem|nei] @ Wg^T (K=2048);
// out = u*state + (1-u)*tanh(cx+accC)*sigmoid(accG+bg)
__global__ void final_k(const __hip_bfloat16* __restrict__ RS,
                        const __hip_bfloat16* __restrict__ Wcb,
                        const __hip_bfloat16* __restrict__ SN,
                        const __hip_bfloat16* __restrict__ Wgt,
                        const __hip_bfloat16* __restrict__ CXb,
                        const __hip_bfloat16* __restrict__ U,
                        const __hip_bfloat16* __restrict__ stbf,  // A1 (state at col 1024+)
                        const float* __restrict__ bg,
                        float* __restrict__ out, int nbx) {
  __shared__ __hip_bfloat16 lA[128 * 64], lB[128 * 64];
  f32x4 acc[4][4];
#pragma unroll
  for (int m = 0; m < 4; ++m)
#pragma unroll
    for (int n = 0; n < 4; ++n) acc[m][n] = (f32x4){0.f, 0.f, 0.f, 0.f};

  const int wg = xcd_map(blockIdx.x, gridDim.x);
  const long mBase = (long)(wg / nbx) * 128;
  const long nBase = (long)(wg % nbx) * 128;
  const int tid = threadIdx.x, wave = tid >> 6, lane = tid & 63;
  const int wr = wave >> 1, wc = wave & 1, lm = lane & 15, hi = lane >> 4;
  const int row0 = (int)mBase + wr * 64 + hi * 4;
  const int col0 = (int)nBase + wc * 64 + lm;

  gemm_acc(RS + mBase * HIDc, HIDc, Wcb + nBase * HIDc, HIDc, 1024, lA, lB, acc);

  float cv[4][4][4];
#pragma unroll
  for (int m = 0; m < 4; ++m)
#pragma unroll
    for (int n = 0; n < 4; ++n)
#pragma unroll
      for (int j = 0; j < 4; ++j) {
        const long row = row0 + m * 16 + j;
        const int col = col0 + n * 16;
        cv[m][n][j] = tanh_fast(__bfloat162float(CXb[row * HIDc + col]) + acc[m][n][j]);
        acc[m][n][j] = 0.f;
      }

  gemm_acc(SN + mBase * 2048, 2048, Wgt + nBase * 2048, 2048, 2048, lA, lB, acc);

#pragma unroll
  for (int m = 0; m < 4; ++m)
#pragma unroll
    for (int n = 0; n < 4; ++n)
#pragma unroll
      for (int j = 0; j < 4; ++j) {
        const long row = row0 + m * 16 + j;
        const int col = col0 + n * 16;
        const long idx = row * HIDc + col;
        float g = sigf(acc[m][n][j] + bg[col]);
        float u = __bfloat162float(U[idx]);
        float st = __bfloat162float(stbf[row * 2048 + 1024 + col]);
        out[idx] = u * st + (1.f - u) * cv[m][n][j] * g;
      }
}

// Pack activations to bf16: A1 = [x | state] (B x 2048), NB = neighbors (B x 1024)
__global__ void convert_k(const float4* __restrict__ in4, const float4* __restrict__ st4,
                          __hip_bfloat16* __restrict__ A1, __hip_bfloat16* __restrict__ NB) {
  const long NI4 = (long)Bsz * 2048 / 4;
  const long NS4 = (long)Bsz * 1024 / 4;
  for (long i = (long)blockIdx.x * blockDim.x + threadIdx.x; i < NI4 + NS4;
       i += (long)gridDim.x * blockDim.x) {
    float4 v;
    __hip_bfloat16* dst;
    if (i < NI4) {
      v = in4[i];
      long e = i << 2;
      long row = e >> 11;
      int col = (int)(e & 2047);
      dst = (col < 1024) ? (A1 + row * 2048 + col) : (NB + row * 1024 + (col - 1024));
    } else {
      long j = i - NI4;
      v = st4[j];
      long e = j << 2;
      long row = e >> 10;
      int col = (int)(e & 1023);
      dst = A1 + row * 2048 + 1024 + col;
    }
    union { __hip_bfloat16 h[4]; s16x4 s; } u;
    u.h[0] = __float2bfloat16(v.x);
    u.h[1] = __float2bfloat16(v.y);
    u.h[2] = __float2bfloat16(v.z);
    u.h[3] = __float2bfloat16(v.w);
    *reinterpret_cast<s16x4*>(dst) = u.s;
  }
}

// out[n*ldout + k] = bf16(in[k*ldin + n]); grid = (K/32, N/32), block = (32,8)
__global__ void transpose_k(const float* __restrict__ in, int ldin,
                            __hip_bfloat16* __restrict__ out, long ldout) {
  __shared__ float t[32][33];
  const int k0 = blockIdx.x * 32, n0 = blockIdx.y * 32;
  const int tx = threadIdx.x, ty = threadIdx.y;
#pragma unroll
  for (int dy = 0; dy < 32; dy += 8)
    t[ty + dy][tx] = in[(long)(k0 + ty + dy) * ldin + n0 + tx];
  __syncthreads();
#pragma unroll
  for (int dy = 0; dy < 32; dy += 8)
    out[(long)(n0 + ty + dy) * ldout + k0 + tx] = __float2bfloat16(t[tx][ty + dy]);
}

extern "C" void kernel_launch(void* const* d_in, const int* in_sizes, int n_in,
                              void* d_out, int out_size, void* d_ws, size_t ws_size,
                              hipStream_t stream) {
  const float* inputs = (const float*)d_in[0];
  const float* state = (const float*)d_in[1];
  const float* Wr = (const float*)d_in[2];
  const float* br = (const float*)d_in[3];
  const float* Wu = (const float*)d_in[4];
  const float* bu = (const float*)d_in[5];
  const float* Wc = (const float*)d_in[6];
  const float* bc = (const float*)d_in[7];
  const float* W1 = (const float*)d_in[8];
  const float* b1 = (const float*)d_in[9];
  const float* W2 = (const float*)d_in[10];
  const float* b2 = (const float*)d_in[11];
  const float* Wg = (const float*)d_in[12];
  const float* bg = (const float*)d_in[13];
  float* out = (float*)d_out;

  char* ws = (char*)d_ws;
  __hip_bfloat16* A1    = (__hip_bfloat16*)(ws);                 // 64 MB [x|state]
  __hip_bfloat16* NB    = (__hip_bfloat16*)(ws + 67108864L);     // 32 MB neighbors
  __hip_bfloat16* RS    = (__hip_bfloat16*)(ws + 100663296L);    // 32 MB r*state
  __hip_bfloat16* Ub    = (__hip_bfloat16*)(ws + 134217728L);    // 32 MB u
  __hip_bfloat16* SN    = (__hip_bfloat16*)(ws + 167772160L);    // 64 MB [sem|nei]
  __hip_bfloat16* CXb   = (__hip_bfloat16*)(ws + 234881024L);    // 32 MB x@Wc_top+bc
  __hip_bfloat16* Wru_t = (__hip_bfloat16*)(ws + 268435456L);    // 8 MB  (2048 x 2048)
  __hip_bfloat16* W1cx_t= (__hip_bfloat16*)(ws + 276824064L);    // 4 MB  (2048 x 1024)
  __hip_bfloat16* Wcb_t = (__hip_bfloat16*)(ws + 281018368L);    // 2 MB  (1024 x 1024)
  __hip_bfloat16* W2_t  = (__hip_bfloat16*)(ws + 283115520L);    // 2 MB  (1024 x 1024)
  __hip_bfloat16* Wg_t  = (__hip_bfloat16*)(ws + 285212672L);    // 4 MB  (1024 x 2048)

  convert_k<<<2048, 256, 0, stream>>>((const float4*)inputs, (const float4*)state, A1, NB);

  dim3 tb(32, 8);
  transpose_k<<<dim3(64, 32), tb, 0, stream>>>(Wr, 1024, Wru_t, 2048);
  transpose_k<<<dim3(64, 32), tb, 0, stream>>>(Wu, 1024, Wru_t + (long)1024 * 2048, 2048);
  transpose_k<<<dim3(32, 32), tb, 0, stream>>>(W1, 1024, W1cx_t, 1024);
  transpose_k<<<dim3(32, 32), tb, 0, stream>>>(Wc, 1024, W1cx_t + (long)1024 * 1024, 1024);
  transpose_k<<<dim3(32, 32), tb, 0, stream>>>(Wc + (long)1024 * 1024, 1024, Wcb_t, 1024);
  transpose_k<<<dim3(32, 32), tb, 0, stream>>>(W2, 1024, W2_t, 1024);
  transpose_k<<<dim3(64, 32), tb, 0, stream>>>(Wg, 1024, Wg_t, 2048);

  // G1: [x|state] @ [Wr|Wu] -> rs, u   (16 n-blocks x 128 m-blocks)
  gemm_k<0><<<2048, 256, 0, stream>>>(A1, 2048, Wru_t, 2048, 2048, 16,
                                      br, bu, A1, RS, Ub);
  // G2: x @ [W1|Wc_top] -> sem, cx
  gemm_k<1><<<2048, 256, 0, stream>>>(A1, 2048, W1cx_t, 1024, 1024, 16,
                                      b1, bc, nullptr, SN, CXb);
  // G3: neighbors @ W2 -> nei
  gemm_k<2><<<1024, 256, 0, stream>>>(NB, 1024, W2_t, 1024, 1024, 8,
                                      b2, nullptr, nullptr, SN, nullptr);
  // G4: dual GEMM + final elementwise
  final_k<<<1024, 256, 0, stream>>>(RS, Wcb_t, SN, Wg_t, CXb, Ub, A1, bg, out, 8);
}

// Round 4
// 524.410 us; speedup vs baseline: 1.7108x; 1.7108x over previous
//
#include <hip/hip_runtime.h>
#include <hip/hip_bf16.h>
#include <math.h>

#define Bsz 16384
#define HIDc 1024

typedef __attribute__((ext_vector_type(8))) short short8_t;
typedef __attribute__((ext_vector_type(4))) float f32x4;
typedef __attribute__((ext_vector_type(4))) short s16x4;

typedef __attribute__((address_space(1))) const unsigned char* gp1_t;
typedef __attribute__((address_space(3))) unsigned char* lp3_t;

__device__ __forceinline__ float sigf(float x) { return 1.0f / (1.0f + __expf(-x)); }
__device__ __forceinline__ float tanh_fast(float x) {
  x = fminf(fmaxf(x, -10.f), 10.f);
  float t = __expf(2.f * x);
  return (t - 1.f) / (t + 1.f);
}

// Bijective XCD-chunked swizzle (T1, m204 form). r2 evidence: final FETCH
// 573 MB -> 280 MB. Keep everywhere.
__device__ __forceinline__ int xcd_map(int bid, int nwg) {
  const int q = nwg >> 3, r = nwg & 7;
  const int xcd = bid & 7, idx = bid >> 3;
  return (xcd < r ? xcd * (q + 1) : r * (q + 1) + (xcd - r) * q) + idx;
}

// Stage a 128x64 bf16 tile (16 KB) into LDS with global_load_lds width=16.
// LDS dest linear; k-slot XOR swizzle applied on the GLOBAL source address
// (both-sides-or-neither, rule #21): phys slot p of row r holds logical p^(r&7).
__device__ __forceinline__ void stage64(const __hip_bfloat16* __restrict__ g, long ld,
                                        __hip_bfloat16* l, int wave, int lane) {
  const int rsub = lane >> 3;                    // row within 8-row chunk
  const int kx = ((lane & 7) ^ rsub) << 3;       // swizzled source col (elems)
#pragma unroll
  for (int i = 0; i < 4; ++i) {
    const int chunk = i * 4 + wave;              // 0..15, 8 rows each
    const int row = chunk * 8 + rsub;
    const __hip_bfloat16* gp = g + (long)row * ld + kx;
    __hip_bfloat16* lp = l + chunk * 512 + lane * 8;   // chunk*1024B + lane*16B
    __builtin_amdgcn_global_load_lds((gp1_t)gp, (lp3_t)lp, 16, 0, 0);
  }
}

// Serial m97-style K-loop (32 KB LDS). r2 post-mortem: 64 KB dbuf halved
// occupancy and regressed — keep the 2-barrier serial schedule.
__device__ __forceinline__ void gemm_acc(const __hip_bfloat16* __restrict__ A, long lda,
                                         const __hip_bfloat16* __restrict__ Wt, long ldw,
                                         int K,
                                         __hip_bfloat16* lA, __hip_bfloat16* lB,
                                         f32x4 acc[4][4]) {
  const int tid = threadIdx.x;
  const int wave = tid >> 6, lane = tid & 63;
  const int wr = wave >> 1, wc = wave & 1;
  const int lm = lane & 15, hi = lane >> 4, l7 = lane & 7;
  for (int k0 = 0; k0 < K; k0 += 64) {
    __syncthreads();                       // previous compute done before overwrite
    stage64(A + k0, lda, lA, wave, lane);
    stage64(Wt + k0, ldw, lB, wave, lane);
    __syncthreads();                       // compiler drains vmcnt before barrier
#pragma unroll
    for (int ks = 0; ks < 2; ++ks) {
      short8_t a8[4], b8[4];
      const int sl = ks * 4 + hi;          // logical 16B slot 0..7
#pragma unroll
      for (int m = 0; m < 4; ++m) {
        const int r = wr * 64 + m * 16 + lm;
        a8[m] = *reinterpret_cast<const short8_t*>(lA + r * 64 + ((sl ^ l7) << 3));
      }
#pragma unroll
      for (int n = 0; n < 4; ++n) {
        const int r = wc * 64 + n * 16 + lm;
        b8[n] = *reinterpret_cast<const short8_t*>(lB + r * 64 + ((sl ^ l7) << 3));
      }
#pragma unroll
      for (int m = 0; m < 4; ++m)
#pragma unroll
        for (int n = 0; n < 4; ++n)
          acc[m][n] = __builtin_amdgcn_mfma_f32_16x16x32_bf16(a8[m], b8[n], acc[m][n], 0, 0, 0);
    }
  }
}

// EPI 0: G1 — col<1024: rs = sigmoid(v+br)*state_bf16 -> out0 (bf16, ld 1024)
//             col>=1024: u = sigmoid(v+bu)            -> out1 (bf16, ld 1024)
// EPI 1: G2 — col<1024: sem = relu(v+b1) -> out0 (bf16, ld 2048)
//             col>=1024: cx = v+bc       -> out1 (bf16, ld 1024)
// EPI 2: G3 — nei = relu(v+b2) -> out0 + 1024 (bf16, ld 2048)
// EPI 3: final_c — cb = tanh(v + auxbf) -> out0 (bf16, ld 1024)
template <int EPI>
__global__ void gemm_k(const __hip_bfloat16* __restrict__ A, long lda,
                       const __hip_bfloat16* __restrict__ Wt, long ldw, int K, int nbx,
                       const float* __restrict__ bias0, const float* __restrict__ bias1,
                       const __hip_bfloat16* __restrict__ stbf,   // A1 (state at col 1024+)
                       const __hip_bfloat16* __restrict__ auxbf,  // EPI3: CXb (ld 1024)
                       __hip_bfloat16* __restrict__ out0, __hip_bfloat16* __restrict__ out1) {
  __shared__ __hip_bfloat16 lA[128 * 64], lB[128 * 64];
  f32x4 acc[4][4];
#pragma unroll
  for (int m = 0; m < 4; ++m)
#pragma unroll
    for (int n = 0; n < 4; ++n) acc[m][n] = (f32x4){0.f, 0.f, 0.f, 0.f};

  const int wg = xcd_map(blockIdx.x, gridDim.x);
  const long mBase = (long)(wg / nbx) * 128;
  const long nBase = (long)(wg % nbx) * 128;
  gemm_acc(A + mBase * lda, lda, Wt + nBase * ldw, ldw, K, lA, lB, acc);

  const int tid = threadIdx.x, wave = tid >> 6, lane = tid & 63;
  const int wr = wave >> 1, wc = wave & 1, lm = lane & 15, hi = lane >> 4;
  const int row0 = (int)mBase + wr * 64 + hi * 4;
  const int col0 = (int)nBase + wc * 64 + lm;
#pragma unroll
  for (int m = 0; m < 4; ++m)
#pragma unroll
    for (int n = 0; n < 4; ++n)
#pragma unroll
      for (int j = 0; j < 4; ++j) {
        const long row = row0 + m * 16 + j;
        const int col = col0 + n * 16;
        const float v = acc[m][n][j];
        if (EPI == 0) {
          if (col < HIDc) {
            float rr = sigf(v + bias0[col]);
            float st = __bfloat162float(stbf[row * 2048 + 1024 + col]);
            out0[row * HIDc + col] = __float2bfloat16(rr * st);
          } else {
            int c = col - HIDc;
            out1[row * HIDc + c] = __float2bfloat16(sigf(v + bias1[c]));
          }
        } else if (EPI == 1) {
          if (col < HIDc) {
            out0[row * 2048 + col] = __float2bfloat16(fmaxf(v + bias0[col], 0.f));
          } else {
            int c = col - HIDc;
            out1[row * HIDc + c] = __float2bfloat16(v + bias1[c]);
          }
        } else if (EPI == 2) {
          out0[row * 2048 + HIDc + col] = __float2bfloat16(fmaxf(v + bias0[col], 0.f));
        } else {
          const long idx = row * HIDc + col;
          float cb = tanh_fast(v + __bfloat162float(auxbf[idx]));
          out0[idx] = __float2bfloat16(cb);
        }
      }
}

// final_g: accG = [sem|nei] @ Wg^T (K=2048);
// out = u*state + (1-u)*cb*sigmoid(accG+bg)   — acc-only live set, no spills.
__global__ void final_g(const __hip_bfloat16* __restrict__ SN,
                        const __hip_bfloat16* __restrict__ Wgt,
                        const __hip_bfloat16* __restrict__ CB,
                        const __hip_bfloat16* __restrict__ U,
                        const __hip_bfloat16* __restrict__ stbf,  // A1 (state at col 1024+)
                        const float* __restrict__ bg,
                        float* __restrict__ out, int nbx) {
  __shared__ __hip_bfloat16 lA[128 * 64], lB[128 * 64];
  f32x4 acc[4][4];
#pragma unroll
  for (int m = 0; m < 4; ++m)
#pragma unroll
    for (int n = 0; n < 4; ++n) acc[m][n] = (f32x4){0.f, 0.f, 0.f, 0.f};

  const int wg = xcd_map(blockIdx.x, gridDim.x);
  const long mBase = (long)(wg / nbx) * 128;
  const long nBase = (long)(wg % nbx) * 128;
  gemm_acc(SN + mBase * 2048, 2048, Wgt + nBase * 2048, 2048, 2048, lA, lB, acc);

  const int tid = threadIdx.x, wave = tid >> 6, lane = tid & 63;
  const int wr = wave >> 1, wc = wave & 1, lm = lane & 15, hi = lane >> 4;
  const int row0 = (int)mBase + wr * 64 + hi * 4;
  const int col0 = (int)nBase + wc * 64 + lm;
#pragma unroll
  for (int m = 0; m < 4; ++m)
#pragma unroll
    for (int n = 0; n < 4; ++n)
#pragma unroll
      for (int j = 0; j < 4; ++j) {
        const long row = row0 + m * 16 + j;
        const int col = col0 + n * 16;
        const long idx = row * HIDc + col;
        float g = sigf(acc[m][n][j] + bg[col]);
        float u = __bfloat162float(U[idx]);
        float cb = __bfloat162float(CB[idx]);
        float st = __bfloat162float(stbf[row * 2048 + 1024 + col]);
        out[idx] = u * st + (1.f - u) * cb * g;
      }
}

// Pack activations to bf16: A1 = [x | state] (B x 2048), NB = neighbors (B x 1024)
__global__ void convert_k(const float4* __restrict__ in4, const float4* __restrict__ st4,
                          __hip_bfloat16* __restrict__ A1, __hip_bfloat16* __restrict__ NB) {
  const long NI4 = (long)Bsz * 2048 / 4;
  const long NS4 = (long)Bsz * 1024 / 4;
  for (long i = (long)blockIdx.x * blockDim.x + threadIdx.x; i < NI4 + NS4;
       i += (long)gridDim.x * blockDim.x) {
    float4 v;
    __hip_bfloat16* dst;
    if (i < NI4) {
      v = in4[i];
      long e = i << 2;
      long row = e >> 11;
      int col = (int)(e & 2047);
      dst = (col < 1024) ? (A1 + row * 2048 + col) : (NB + row * 1024 + (col - 1024));
    } else {
      long j = i - NI4;
      v = st4[j];
      long e = j << 2;
      long row = e >> 10;
      int col = (int)(e & 1023);
      dst = A1 + row * 2048 + 1024 + col;
    }
    union { __hip_bfloat16 h[4]; s16x4 s; } u;
    u.h[0] = __float2bfloat16(v.x);
    u.h[1] = __float2bfloat16(v.y);
    u.h[2] = __float2bfloat16(v.z);
    u.h[3] = __float2bfloat16(v.w);
    *reinterpret_cast<s16x4*>(dst) = u.s;
  }
}

// out[n*ldout + k] = bf16(in[k*ldin + n]); grid = (K/32, N/32), block = (32,8)
__global__ void transpose_k(const float* __restrict__ in, int ldin,
                            __hip_bfloat16* __restrict__ out, long ldout) {
  __shared__ float t[32][33];
  const int k0 = blockIdx.x * 32, n0 = blockIdx.y * 32;
  const int tx = threadIdx.x, ty = threadIdx.y;
#pragma unroll
  for (int dy = 0; dy < 32; dy += 8)
    t[ty + dy][tx] = in[(long)(k0 + ty + dy) * ldin + n0 + tx];
  __syncthreads();
#pragma unroll
  for (int dy = 0; dy < 32; dy += 8)
    out[(long)(n0 + ty + dy) * ldout + k0 + tx] = __float2bfloat16(t[tx][ty + dy]);
}

extern "C" void kernel_launch(void* const* d_in, const int* in_sizes, int n_in,
                              void* d_out, int out_size, void* d_ws, size_t ws_size,
                              hipStream_t stream) {
  const float* inputs = (const float*)d_in[0];
  const float* state = (const float*)d_in[1];
  const float* Wr = (const float*)d_in[2];
  const float* br = (const float*)d_in[3];
  const float* Wu = (const float*)d_in[4];
  const float* bu = (const float*)d_in[5];
  const float* Wc = (const float*)d_in[6];
  const float* bc = (const float*)d_in[7];
  const float* W1 = (const float*)d_in[8];
  const float* b1 = (const float*)d_in[9];
  const float* W2 = (const float*)d_in[10];
  const float* b2 = (const float*)d_in[11];
  const float* Wg = (const float*)d_in[12];
  const float* bg = (const float*)d_in[13];
  float* out = (float*)d_out;

  char* ws = (char*)d_ws;
  __hip_bfloat16* A1    = (__hip_bfloat16*)(ws);                 // 64 MB [x|state]
  __hip_bfloat16* NB    = (__hip_bfloat16*)(ws + 67108864L);     // 32 MB neighbors -> CB after G3
  __hip_bfloat16* RS    = (__hip_bfloat16*)(ws + 100663296L);    // 32 MB r*state
  __hip_bfloat16* Ub    = (__hip_bfloat16*)(ws + 134217728L);    // 32 MB u
  __hip_bfloat16* SN    = (__hip_bfloat16*)(ws + 167772160L);    // 64 MB [sem|nei]
  __hip_bfloat16* CXb   = (__hip_bfloat16*)(ws + 234881024L);    // 32 MB x@Wc_top+bc
  __hip_bfloat16* Wru_t = (__hip_bfloat16*)(ws + 268435456L);    // 8 MB  (2048 x 2048)
  __hip_bfloat16* W1cx_t= (__hip_bfloat16*)(ws + 276824064L);    // 4 MB  (2048 x 1024)
  __hip_bfloat16* Wcb_t = (__hip_bfloat16*)(ws + 281018368L);    // 2 MB  (1024 x 1024)
  __hip_bfloat16* W2_t  = (__hip_bfloat16*)(ws + 283115520L);    // 2 MB  (1024 x 1024)
  __hip_bfloat16* Wg_t  = (__hip_bfloat16*)(ws + 285212672L);    // 4 MB  (1024 x 2048)
  __hip_bfloat16* CB    = NB;   // NB is dead after G3; reuse for tanh(c) output

  convert_k<<<2048, 256, 0, stream>>>((const float4*)inputs, (const float4*)state, A1, NB);

  dim3 tb(32, 8);
  transpose_k<<<dim3(64, 32), tb, 0, stream>>>(Wr, 1024, Wru_t, 2048);
  transpose_k<<<dim3(64, 32), tb, 0, stream>>>(Wu, 1024, Wru_t + (long)1024 * 2048, 2048);
  transpose_k<<<dim3(32, 32), tb, 0, stream>>>(W1, 1024, W1cx_t, 1024);
  transpose_k<<<dim3(32, 32), tb, 0, stream>>>(Wc, 1024, W1cx_t + (long)1024 * 1024, 1024);
  transpose_k<<<dim3(32, 32), tb, 0, stream>>>(Wc + (long)1024 * 1024, 1024, Wcb_t, 1024);
  transpose_k<<<dim3(32, 32), tb, 0, stream>>>(W2, 1024, W2_t, 1024);
  transpose_k<<<dim3(64, 32), tb, 0, stream>>>(Wg, 1024, Wg_t, 2048);

  // G1: [x|state] @ [Wr|Wu] -> rs, u   (16 n-blocks x 128 m-blocks)
  gemm_k<0><<<2048, 256, 0, stream>>>(A1, 2048, Wru_t, 2048, 2048, 16,
                                      br, bu, A1, nullptr, RS, Ub);
  // G2: x @ [W1|Wc_top] -> sem, cx
  gemm_k<1><<<2048, 256, 0, stream>>>(A1, 2048, W1cx_t, 1024, 1024, 16,
                                      b1, bc, nullptr, nullptr, SN, CXb);
  // G3: neighbors @ W2 -> nei  (reads NB; CB overwrite happens after)
  gemm_k<2><<<1024, 256, 0, stream>>>(NB, 1024, W2_t, 1024, 1024, 8,
                                      b2, nullptr, nullptr, nullptr, SN, nullptr);
  // final_c: cb = tanh(cx + rs @ Wc_bot^T) -> CB (bf16)
  gemm_k<3><<<1024, 256, 0, stream>>>(RS, 1024, Wcb_t, 1024, 1024, 8,
                                      nullptr, nullptr, nullptr, CXb, CB, nullptr);
  // final_g: out = u*state + (1-u)*cb*sigmoid([sem|nei] @ Wg^T + bg)
  final_g<<<1024, 256, 0, stream>>>(SN, Wg_t, CB, Ub, A1, bg, out, 8);
}